// Round 5
// baseline (304.307 us; speedup 1.0000x reference)
//
#include <hip/hip_runtime.h>
#include <math.h>

// ---------------------------------------------------------------------------
// 2-layer GAT encoder. CSR-by-dst gather aggregation (atomic-free).
// Round-5 change:
//  * Round-4's unrolled gather loop spilled to scratch at the default
//    64-VGPR budget (WRITE_SIZE 7->96 MB, pure spill traffic).
//    __launch_bounds__(256,4) raises the cap to 128 VGPR/lane (still 50%
//    occupancy) -> no spill, no scratch write-back, L2 stays clean for
//    the h1b gather working set.
// ---------------------------------------------------------------------------

__device__ __forceinline__ float leaky02(float x) { return x > 0.f ? x : 0.2f * x; }
__device__ __forceinline__ float eluf(float x) { return x > 0.f ? x : expm1f(x); }
__device__ __forceinline__ float waveReduceSum(float v) {
#pragma unroll
    for (int off = 32; off; off >>= 1) v += __shfl_xor(v, off, 64);
    return v;
}
__device__ __forceinline__ unsigned short f2bf(float f) {
    unsigned u = __float_as_uint(f);
    u += 0x7FFFu + ((u >> 16) & 1u);
    return (unsigned short)(u >> 16);
}
__device__ __forceinline__ float bf2f(unsigned short h) {
    return __uint_as_float((unsigned)h << 16);
}

// ---------------- CSR construction ----------------

__global__ void k_deg(const int* __restrict__ dst, int* __restrict__ deg, int e_cnt) {
    int e = blockIdx.x * blockDim.x + threadIdx.x;
    if (e < e_cnt) atomicAdd(&deg[dst[e]], 1);
}

__global__ void k_scan_bsums(const int* __restrict__ deg, int* __restrict__ bsum, int n) {
    __shared__ int part[4];
    int i = blockIdx.x * 256 + threadIdx.x;
    int v = (i < n) ? deg[i] : 0;
    int w = v;
#pragma unroll
    for (int off = 32; off; off >>= 1) w += __shfl_xor(w, off, 64);
    if ((threadIdx.x & 63) == 0) part[threadIdx.x >> 6] = w;
    __syncthreads();
    if (threadIdx.x == 0) bsum[blockIdx.x] = part[0] + part[1] + part[2] + part[3];
}

__global__ void k_scan_bofs(const int* __restrict__ bsum, int* __restrict__ bofs, int nb) {
    __shared__ int s[256];
    int t = threadIdx.x;
    int v = (t < nb) ? bsum[t] : 0;
    s[t] = v;
    __syncthreads();
#pragma unroll
    for (int d = 1; d < 256; d <<= 1) {
        int add = (t >= d) ? s[t - d] : 0;
        __syncthreads();
        s[t] += add;
        __syncthreads();
    }
    bofs[t] = s[t] - v;  // exclusive
}

__global__ void k_scan_final(const int* __restrict__ deg, const int* __restrict__ bofs,
                             int* __restrict__ off, int* __restrict__ cursor, int n, int e_cnt) {
    __shared__ int s[256];
    int t = threadIdx.x;
    int i = blockIdx.x * 256 + t;
    int v = (i < n) ? deg[i] : 0;
    s[t] = v;
    __syncthreads();
#pragma unroll
    for (int d = 1; d < 256; d <<= 1) {
        int add = (t >= d) ? s[t - d] : 0;
        __syncthreads();
        s[t] += add;
        __syncthreads();
    }
    int o = bofs[blockIdx.x] + s[t] - v;
    if (i < n) { off[i] = o; cursor[i] = o; }
    if (i == 0) off[n] = e_cnt;
}

// K3: pure permutation scatter: CSR slot -> source node id.
__global__ void k3_scatter(const int* __restrict__ src, const int* __restrict__ dst,
                           int* __restrict__ cursor, int* __restrict__ csr_src, int e_cnt) {
    int e = blockIdx.x * blockDim.x + threadIdx.x;
    if (e >= e_cnt) return;
    int pos = atomicAdd(&cursor[dst[e]], 1);
    csr_src[pos] = src[e];
}

// ---------------- Layer 1 ----------------

// K1: h1b (bf16, [N,256], channel c = 4*lane+j); a_src1/a_dst1 [N,4] fp32.
__global__ void k1_gemm1(const float* __restrict__ x, const float* __restrict__ W1,
                         const float* __restrict__ attS, const float* __restrict__ attD,
                         unsigned short* __restrict__ h1b, float* __restrict__ a_src1,
                         float* __restrict__ a_dst1, int n_nodes) {
    __shared__ float W1s[16 * 256];
    for (int i = threadIdx.x; i < 16 * 256; i += 256) W1s[i] = W1[i];
    __syncthreads();
    const int wave = threadIdx.x >> 6, lane = threadIdx.x & 63;
    const float4 aS = ((const float4*)attS)[lane];
    const float4 aD = ((const float4*)attD)[lane];
    for (int n = blockIdx.x * 4 + wave; n < n_nodes; n += gridDim.x * 4) {
        float xv = x[(size_t)n * 16 + (lane & 15)];
        float v0 = 0.f, v1 = 0.f, v2 = 0.f, v3 = 0.f;
#pragma unroll
        for (int k = 0; k < 16; ++k) {
            float xk = __shfl(xv, k, 64);
            const float* w = W1s + k * 256 + 4 * lane;
            v0 += xk * w[0]; v1 += xk * w[1]; v2 += xk * w[2]; v3 += xk * w[3];
        }
        ushort4 q;
        q.x = f2bf(v0); q.y = f2bf(v1); q.z = f2bf(v2); q.w = f2bf(v3);
        ((ushort4*)(h1b + (size_t)n * 256))[lane] = q;
        float ps = v0 * aS.x + v1 * aS.y + v2 * aS.z + v3 * aS.w;
        float pd = v0 * aD.x + v1 * aD.y + v2 * aD.z + v3 * aD.w;
#pragma unroll
        for (int off = 1; off < 16; off <<= 1) {
            ps += __shfl_xor(ps, off, 64);
            pd += __shfl_xor(pd, off, 64);
        }
        if ((lane & 15) == 0) {
            a_src1[n * 4 + (lane >> 4)] = ps;
            a_dst1[n * 4 + (lane >> 4)] = pd;
        }
    }
}

// K4: fused layer-1 softmax-gather + head-mean + b1 + ELU + GEMM2 + L2 scores.
// Wave per dst node; lane owns channels 4l..4l+3 (head = lane>>4).
// Chunked (16 edges): coalesced preload of src + per-head exp, shfl broadcast,
// inner loop unrolled x4 for memory-level parallelism.
// launch_bounds(256,4): 128 VGPR cap -> no scratch spill (round-4 lesson).
__global__ void __launch_bounds__(256, 4)
k4_agg1(const int* __restrict__ off, const int* __restrict__ csr_src,
        const unsigned short* __restrict__ h1b,
        const float* __restrict__ a_src1, const float* __restrict__ a_dst1,
        const float* __restrict__ b1, const float* __restrict__ W2,
        const float* __restrict__ attS2, const float* __restrict__ attD2,
        unsigned short* __restrict__ h2b, float* __restrict__ a_src2,
        float* __restrict__ a_dst2, int n_nodes) {
    __shared__ float W2s[64 * 64];
    __shared__ float as2s[64], ad2s[64];
    for (int i = threadIdx.x; i < 64 * 64; i += 256) W2s[i] = W2[i];
    if (threadIdx.x < 64) {
        as2s[threadIdx.x] = attS2[threadIdx.x];
        ad2s[threadIdx.x] = attD2[threadIdx.x];
    }
    __syncthreads();
    const int wave = threadIdx.x >> 6, lane = threadIdx.x & 63;
    const int head = lane >> 4;
    const int grp = lane & 48;  // head*16
    const float4 b1v = ((const float4*)b1)[lane & 15];
    for (int n = blockIdx.x * 4 + wave; n < n_nodes; n += gridDim.x * 4) {
        int beg = off[n], end = off[n + 1];
        float4 as = *(const float4*)(a_src1 + (size_t)n * 4);
        float4 ad = *(const float4*)(a_dst1 + (size_t)n * 4);
        float adh = head == 0 ? ad.x : head == 1 ? ad.y : head == 2 ? ad.z : ad.w;
        float ash = head == 0 ? as.x : head == 1 ? as.y : head == 2 ? as.z : as.w;
        float se = expf(leaky02(ash + adh));
        ushort4 qs = ((const ushort4*)(h1b + (size_t)n * 256))[lane];
        float den = se;
        float a0 = se * bf2f(qs.x), a1 = se * bf2f(qs.y);
        float a2 = se * bf2f(qs.z), a3 = se * bf2f(qs.w);
        for (int base = beg; base < end; base += 16) {
            int m = end - base; if (m > 16) m = 16;
            int s16 = 0; float exh_pre = 0.f;
            if ((lane & 15) < m) {
                s16 = csr_src[base + (lane & 15)];
                float av = a_src1[4 * s16 + head];
                exh_pre = expf(leaky02(av + adh));
            }
            int i = 0;
            for (; i + 4 <= m; i += 4) {
                int s0 = __shfl(s16, i, 64);
                int s1 = __shfl(s16, i + 1, 64);
                int s2 = __shfl(s16, i + 2, 64);
                int s3 = __shfl(s16, i + 3, 64);
                float e0 = __shfl(exh_pre, grp | i, 64);
                float e1 = __shfl(exh_pre, grp | (i + 1), 64);
                float e2 = __shfl(exh_pre, grp | (i + 2), 64);
                float e3 = __shfl(exh_pre, grp | (i + 3), 64);
                ushort4 q0 = ((const ushort4*)(h1b + (size_t)s0 * 256))[lane];
                ushort4 q1 = ((const ushort4*)(h1b + (size_t)s1 * 256))[lane];
                ushort4 q2 = ((const ushort4*)(h1b + (size_t)s2 * 256))[lane];
                ushort4 q3 = ((const ushort4*)(h1b + (size_t)s3 * 256))[lane];
                a0 += e0 * bf2f(q0.x) + e1 * bf2f(q1.x) + e2 * bf2f(q2.x) + e3 * bf2f(q3.x);
                a1 += e0 * bf2f(q0.y) + e1 * bf2f(q1.y) + e2 * bf2f(q2.y) + e3 * bf2f(q3.y);
                a2 += e0 * bf2f(q0.z) + e1 * bf2f(q1.z) + e2 * bf2f(q2.z) + e3 * bf2f(q3.z);
                a3 += e0 * bf2f(q0.w) + e1 * bf2f(q1.w) + e2 * bf2f(q2.w) + e3 * bf2f(q3.w);
                den += e0 + e1 + e2 + e3;
            }
            for (; i < m; ++i) {
                int s = __shfl(s16, i, 64);
                float eh = __shfl(exh_pre, grp | i, 64);
                ushort4 q = ((const ushort4*)(h1b + (size_t)s * 256))[lane];
                a0 += eh * bf2f(q.x); a1 += eh * bf2f(q.y);
                a2 += eh * bf2f(q.z); a3 += eh * bf2f(q.w);
                den += eh;
            }
        }
        float inv = 1.f / (den + 1e-16f);
        float t0 = a0 * inv, t1 = a1 * inv, t2 = a2 * inv, t3 = a3 * inv;
        t0 += __shfl_xor(t0, 16, 64); t0 += __shfl_xor(t0, 32, 64);
        t1 += __shfl_xor(t1, 16, 64); t1 += __shfl_xor(t1, 32, 64);
        t2 += __shfl_xor(t2, 16, 64); t2 += __shfl_xor(t2, 32, 64);
        t3 += __shfl_xor(t3, 16, 64); t3 += __shfl_xor(t3, 32, 64);
        float x20 = eluf(0.25f * t0 + b1v.x);
        float x21 = eluf(0.25f * t1 + b1v.y);
        float x22 = eluf(0.25f * t2 + b1v.z);
        float x23 = eluf(0.25f * t3 + b1v.w);
        float g = 0.f;
#pragma unroll
        for (int qq = 0; qq < 16; ++qq) {
            float xk0 = __shfl(x20, qq, 64);
            float xk1 = __shfl(x21, qq, 64);
            float xk2 = __shfl(x22, qq, 64);
            float xk3 = __shfl(x23, qq, 64);
            const float* w = W2s + (4 * qq) * 64 + lane;
            g += xk0 * w[0] + xk1 * w[64] + xk2 * w[128] + xk3 * w[192];
        }
        h2b[(size_t)n * 64 + lane] = f2bf(g);
        float ps = waveReduceSum(g * as2s[lane]);
        float pd = waveReduceSum(g * ad2s[lane]);
        if (lane == 0) {
            a_src2[n] = ps;
            a_dst2[n] = pd;
        }
    }
}

// ---------------- Layer 2 ----------------

// K8: fused layer-2 softmax-gather + self message + b2 + ELU -> out.
// Chunked (64 edges): coalesced preload of src + exp, shfl broadcast, x4 unroll.
__global__ void __launch_bounds__(256, 4)
k8_agg2(const int* __restrict__ off, const int* __restrict__ csr_src,
        const unsigned short* __restrict__ h2b,
        const float* __restrict__ a_src2, const float* __restrict__ a_dst2,
        const float* __restrict__ b2, float* __restrict__ out, int n_nodes) {
    __shared__ float b2s[64];
    if (threadIdx.x < 64) b2s[threadIdx.x] = b2[threadIdx.x];
    __syncthreads();
    const int wave = threadIdx.x >> 6, lane = threadIdx.x & 63;
    for (int n = blockIdx.x * 4 + wave; n < n_nodes; n += gridDim.x * 4) {
        int beg = off[n], end = off[n + 1];
        float adn = a_dst2[n];
        float se = expf(leaky02(a_src2[n] + adn));
        float den = se;
        float acc = se * bf2f(h2b[(size_t)n * 64 + lane]);
        for (int base = beg; base < end; base += 64) {
            int m = end - base; if (m > 64) m = 64;
            int s64 = 0; float exl = 0.f;
            if (lane < m) {
                s64 = csr_src[base + lane];
                exl = expf(leaky02(a_src2[s64] + adn));
            }
            int i = 0;
            for (; i + 4 <= m; i += 4) {
                int s0 = __shfl(s64, i, 64);
                int s1 = __shfl(s64, i + 1, 64);
                int s2 = __shfl(s64, i + 2, 64);
                int s3 = __shfl(s64, i + 3, 64);
                float e0 = __shfl(exl, i, 64);
                float e1 = __shfl(exl, i + 1, 64);
                float e2 = __shfl(exl, i + 2, 64);
                float e3 = __shfl(exl, i + 3, 64);
                float q0 = bf2f(h2b[(size_t)s0 * 64 + lane]);
                float q1 = bf2f(h2b[(size_t)s1 * 64 + lane]);
                float q2 = bf2f(h2b[(size_t)s2 * 64 + lane]);
                float q3 = bf2f(h2b[(size_t)s3 * 64 + lane]);
                acc += e0 * q0 + e1 * q1 + e2 * q2 + e3 * q3;
                den += e0 + e1 + e2 + e3;
            }
            for (; i < m; ++i) {
                int s = __shfl(s64, i, 64);
                float eh = __shfl(exl, i, 64);
                acc += eh * bf2f(h2b[(size_t)s * 64 + lane]);
                den += eh;
            }
        }
        out[(size_t)n * 64 + lane] = eluf(acc / (den + 1e-16f) + b2s[lane]);
    }
}

extern "C" void kernel_launch(void* const* d_in, const int* in_sizes, int n_in,
                              void* d_out, int out_size, void* d_ws, size_t ws_size,
                              hipStream_t stream) {
    const float* x   = (const float*)d_in[0];
    const int*   ei  = (const int*)d_in[1];
    const float* W1  = (const float*)d_in[2];
    const float* as1 = (const float*)d_in[3];
    const float* ad1 = (const float*)d_in[4];
    const float* b1  = (const float*)d_in[5];
    const float* W2  = (const float*)d_in[6];
    const float* as2 = (const float*)d_in[7];
    const float* ad2 = (const float*)d_in[8];
    const float* b2  = (const float*)d_in[9];
    float* out = (float*)d_out;

    const int n = in_sizes[0] / 16;   // 50000
    const int e = in_sizes[1] / 2;    // 400000
    const int* src = ei;
    const int* dst = ei + e;
    const int nb = (n + 255) / 256;

    float* ws = (float*)d_ws;
    size_t o = 0;
    unsigned short* h1b = (unsigned short*)(ws + o); o += (size_t)n * 128;  // [N,256] bf16
    float*  a_src1  = ws + o; o += (size_t)n * 4;
    float*  a_dst1  = ws + o; o += (size_t)n * 4;
    unsigned short* h2b = (unsigned short*)(ws + o); o += (size_t)n * 32;   // [N,64] bf16
    float*  a_src2  = ws + o; o += (size_t)n;
    float*  a_dst2  = ws + o; o += (size_t)n;
    int*    csr_src = (int*)(ws + o); o += (size_t)e;
    int*    deg     = (int*)(ws + o); o += (size_t)n;
    int*    off     = (int*)(ws + o); o += (size_t)(n + 4);
    int*    cursor  = (int*)(ws + o); o += (size_t)n;
    int*    bsum    = (int*)(ws + o); o += 256;
    int*    bofs    = (int*)(ws + o); o += 256;

    hipMemsetAsync(deg, 0, (size_t)n * sizeof(int), stream);

    // CSR build (independent of features)
    k_deg<<<(e + 255) / 256, 256, 0, stream>>>(dst, deg, e);
    k_scan_bsums<<<nb, 256, 0, stream>>>(deg, bsum, n);
    k_scan_bofs<<<1, 256, 0, stream>>>(bsum, bofs, nb);
    k_scan_final<<<nb, 256, 0, stream>>>(deg, bofs, off, cursor, n, e);
    k3_scatter<<<(e + 255) / 256, 256, 0, stream>>>(src, dst, cursor, csr_src, e);

    // Layer 1
    k1_gemm1<<<(n + 3) / 4, 256, 0, stream>>>(x, W1, as1, ad1, h1b, a_src1, a_dst1, n);
    k4_agg1<<<(n + 3) / 4, 256, 0, stream>>>(off, csr_src, h1b, a_src1, a_dst1,
                                             b1, W2, as2, ad2, h2b, a_src2, a_dst2, n);

    // Layer 2
    k8_agg2<<<(n + 3) / 4, 256, 0, stream>>>(off, csr_src, h2b, a_src2, a_dst2, b2, out, n);
}

// Round 6
// 299.466 us; speedup vs baseline: 1.0162x; 1.0162x over previous
//
#include <hip/hip_runtime.h>
#include <math.h>

// ---------------------------------------------------------------------------
// 2-layer GAT encoder. CSR-by-dst gather aggregation (atomic-free).
// Round-6 change:
//  * Rounds 4/5 spilled ~28 B/lane of chunk-preload state to scratch
//    (WRITE_SIZE 7->96 MB; launch_bounds didn't change the allocator's
//    choice). The chunk exchange now goes through LDS: each lane stores its
//    (head,edge) exp once, lanes 0-15 store the src ids; the unrolled inner
//    loop reads them back as broadcast LDS loads. Only the 5 accumulators
//    stay live across the chunk -> no spill, no scratch stream.
// ---------------------------------------------------------------------------

__device__ __forceinline__ float leaky02(float x) { return x > 0.f ? x : 0.2f * x; }
__device__ __forceinline__ float eluf(float x) { return x > 0.f ? x : expm1f(x); }
__device__ __forceinline__ float waveReduceSum(float v) {
#pragma unroll
    for (int off = 32; off; off >>= 1) v += __shfl_xor(v, off, 64);
    return v;
}
__device__ __forceinline__ unsigned short f2bf(float f) {
    unsigned u = __float_as_uint(f);
    u += 0x7FFFu + ((u >> 16) & 1u);
    return (unsigned short)(u >> 16);
}
__device__ __forceinline__ float bf2f(unsigned short h) {
    return __uint_as_float((unsigned)h << 16);
}

// ---------------- CSR construction ----------------

__global__ void k_deg(const int* __restrict__ dst, int* __restrict__ deg, int e_cnt) {
    int e = blockIdx.x * blockDim.x + threadIdx.x;
    if (e < e_cnt) atomicAdd(&deg[dst[e]], 1);
}

__global__ void k_scan_bsums(const int* __restrict__ deg, int* __restrict__ bsum, int n) {
    __shared__ int part[4];
    int i = blockIdx.x * 256 + threadIdx.x;
    int v = (i < n) ? deg[i] : 0;
    int w = v;
#pragma unroll
    for (int off = 32; off; off >>= 1) w += __shfl_xor(w, off, 64);
    if ((threadIdx.x & 63) == 0) part[threadIdx.x >> 6] = w;
    __syncthreads();
    if (threadIdx.x == 0) bsum[blockIdx.x] = part[0] + part[1] + part[2] + part[3];
}

__global__ void k_scan_bofs(const int* __restrict__ bsum, int* __restrict__ bofs, int nb) {
    __shared__ int s[256];
    int t = threadIdx.x;
    int v = (t < nb) ? bsum[t] : 0;
    s[t] = v;
    __syncthreads();
#pragma unroll
    for (int d = 1; d < 256; d <<= 1) {
        int add = (t >= d) ? s[t - d] : 0;
        __syncthreads();
        s[t] += add;
        __syncthreads();
    }
    bofs[t] = s[t] - v;  // exclusive
}

__global__ void k_scan_final(const int* __restrict__ deg, const int* __restrict__ bofs,
                             int* __restrict__ off, int* __restrict__ cursor, int n, int e_cnt) {
    __shared__ int s[256];
    int t = threadIdx.x;
    int i = blockIdx.x * 256 + t;
    int v = (i < n) ? deg[i] : 0;
    s[t] = v;
    __syncthreads();
#pragma unroll
    for (int d = 1; d < 256; d <<= 1) {
        int add = (t >= d) ? s[t - d] : 0;
        __syncthreads();
        s[t] += add;
        __syncthreads();
    }
    int o = bofs[blockIdx.x] + s[t] - v;
    if (i < n) { off[i] = o; cursor[i] = o; }
    if (i == 0) off[n] = e_cnt;
}

// K3: pure permutation scatter: CSR slot -> source node id.
__global__ void k3_scatter(const int* __restrict__ src, const int* __restrict__ dst,
                           int* __restrict__ cursor, int* __restrict__ csr_src, int e_cnt) {
    int e = blockIdx.x * blockDim.x + threadIdx.x;
    if (e >= e_cnt) return;
    int pos = atomicAdd(&cursor[dst[e]], 1);
    csr_src[pos] = src[e];
}

// ---------------- Layer 1 ----------------

// K1: h1b (bf16, [N,256], channel c = 4*lane+j); a_src1/a_dst1 [N,4] fp32.
__global__ void k1_gemm1(const float* __restrict__ x, const float* __restrict__ W1,
                         const float* __restrict__ attS, const float* __restrict__ attD,
                         unsigned short* __restrict__ h1b, float* __restrict__ a_src1,
                         float* __restrict__ a_dst1, int n_nodes) {
    __shared__ float W1s[16 * 256];
    for (int i = threadIdx.x; i < 16 * 256; i += 256) W1s[i] = W1[i];
    __syncthreads();
    const int wave = threadIdx.x >> 6, lane = threadIdx.x & 63;
    const float4 aS = ((const float4*)attS)[lane];
    const float4 aD = ((const float4*)attD)[lane];
    for (int n = blockIdx.x * 4 + wave; n < n_nodes; n += gridDim.x * 4) {
        float xv = x[(size_t)n * 16 + (lane & 15)];
        float v0 = 0.f, v1 = 0.f, v2 = 0.f, v3 = 0.f;
#pragma unroll
        for (int k = 0; k < 16; ++k) {
            float xk = __shfl(xv, k, 64);
            const float* w = W1s + k * 256 + 4 * lane;
            v0 += xk * w[0]; v1 += xk * w[1]; v2 += xk * w[2]; v3 += xk * w[3];
        }
        ushort4 q;
        q.x = f2bf(v0); q.y = f2bf(v1); q.z = f2bf(v2); q.w = f2bf(v3);
        ((ushort4*)(h1b + (size_t)n * 256))[lane] = q;
        float ps = v0 * aS.x + v1 * aS.y + v2 * aS.z + v3 * aS.w;
        float pd = v0 * aD.x + v1 * aD.y + v2 * aD.z + v3 * aD.w;
#pragma unroll
        for (int off = 1; off < 16; off <<= 1) {
            ps += __shfl_xor(ps, off, 64);
            pd += __shfl_xor(pd, off, 64);
        }
        if ((lane & 15) == 0) {
            a_src1[n * 4 + (lane >> 4)] = ps;
            a_dst1[n * 4 + (lane >> 4)] = pd;
        }
    }
}

// K4: fused layer-1 softmax-gather + head-mean + b1 + ELU + GEMM2 + L2 scores.
// Wave per dst node; lane owns channels 4l..4l+3 (head = lane>>4).
// Chunked (16 edges): coalesced preload of src + per-head exp into LDS,
// broadcast LDS reads in the x4-unrolled gather loop (no shfl, no live
// chunk state in VGPRs -> no spill).
__global__ void __launch_bounds__(256, 4)
k4_agg1(const int* __restrict__ off, const int* __restrict__ csr_src,
        const unsigned short* __restrict__ h1b,
        const float* __restrict__ a_src1, const float* __restrict__ a_dst1,
        const float* __restrict__ b1, const float* __restrict__ W2,
        const float* __restrict__ attS2, const float* __restrict__ attD2,
        unsigned short* __restrict__ h2b, float* __restrict__ a_src2,
        float* __restrict__ a_dst2, int n_nodes) {
    __shared__ float W2s[64 * 64];
    __shared__ float as2s[64], ad2s[64];
    __shared__ int   sS[4][16];   // per-wave chunk src ids
    __shared__ float eS[4][64];   // per-wave chunk exp, [head*16+j]
    for (int i = threadIdx.x; i < 64 * 64; i += 256) W2s[i] = W2[i];
    if (threadIdx.x < 64) {
        as2s[threadIdx.x] = attS2[threadIdx.x];
        ad2s[threadIdx.x] = attD2[threadIdx.x];
    }
    __syncthreads();
    const int wave = threadIdx.x >> 6, lane = threadIdx.x & 63;
    const int head = lane >> 4;
    const int grp = lane & 48;  // head*16
    const int j = lane & 15;
    const float4 b1v = ((const float4*)b1)[j];
    for (int n = blockIdx.x * 4 + wave; n < n_nodes; n += gridDim.x * 4) {
        int beg = off[n], end = off[n + 1];
        float4 as = *(const float4*)(a_src1 + (size_t)n * 4);
        float4 ad = *(const float4*)(a_dst1 + (size_t)n * 4);
        float adh = head == 0 ? ad.x : head == 1 ? ad.y : head == 2 ? ad.z : ad.w;
        float ash = head == 0 ? as.x : head == 1 ? as.y : head == 2 ? as.z : as.w;
        float se = expf(leaky02(ash + adh));
        ushort4 qs = ((const ushort4*)(h1b + (size_t)n * 256))[lane];
        float den = se;
        float a0 = se * bf2f(qs.x), a1 = se * bf2f(qs.y);
        float a2 = se * bf2f(qs.z), a3 = se * bf2f(qs.w);
        for (int base = beg; base < end; base += 16) {
            int m = end - base; if (m > 16) m = 16;
            // preload into LDS: lane (head,j) computes exp for edge base+j, head
            if (j < m) {
                int s = csr_src[base + j];
                if (lane < 16) sS[wave][j] = s;
                float av = a_src1[4 * s + head];
                eS[wave][lane] = expf(leaky02(av + adh));
            }
            int i = 0;
            for (; i + 4 <= m; i += 4) {
                int s0 = sS[wave][i];
                int s1 = sS[wave][i + 1];
                int s2 = sS[wave][i + 2];
                int s3 = sS[wave][i + 3];
                ushort4 q0 = ((const ushort4*)(h1b + (size_t)s0 * 256))[lane];
                ushort4 q1 = ((const ushort4*)(h1b + (size_t)s1 * 256))[lane];
                ushort4 q2 = ((const ushort4*)(h1b + (size_t)s2 * 256))[lane];
                ushort4 q3 = ((const ushort4*)(h1b + (size_t)s3 * 256))[lane];
                float e0 = eS[wave][grp | i];
                float e1 = eS[wave][grp | (i + 1)];
                float e2 = eS[wave][grp | (i + 2)];
                float e3 = eS[wave][grp | (i + 3)];
                a0 += e0 * bf2f(q0.x) + e1 * bf2f(q1.x) + e2 * bf2f(q2.x) + e3 * bf2f(q3.x);
                a1 += e0 * bf2f(q0.y) + e1 * bf2f(q1.y) + e2 * bf2f(q2.y) + e3 * bf2f(q3.y);
                a2 += e0 * bf2f(q0.z) + e1 * bf2f(q1.z) + e2 * bf2f(q2.z) + e3 * bf2f(q3.z);
                a3 += e0 * bf2f(q0.w) + e1 * bf2f(q1.w) + e2 * bf2f(q2.w) + e3 * bf2f(q3.w);
                den += e0 + e1 + e2 + e3;
            }
            for (; i < m; ++i) {
                int s = sS[wave][i];
                float eh = eS[wave][grp | i];
                ushort4 q = ((const ushort4*)(h1b + (size_t)s * 256))[lane];
                a0 += eh * bf2f(q.x); a1 += eh * bf2f(q.y);
                a2 += eh * bf2f(q.z); a3 += eh * bf2f(q.w);
                den += eh;
            }
        }
        float inv = 1.f / (den + 1e-16f);
        float t0 = a0 * inv, t1 = a1 * inv, t2 = a2 * inv, t3 = a3 * inv;
        t0 += __shfl_xor(t0, 16, 64); t0 += __shfl_xor(t0, 32, 64);
        t1 += __shfl_xor(t1, 16, 64); t1 += __shfl_xor(t1, 32, 64);
        t2 += __shfl_xor(t2, 16, 64); t2 += __shfl_xor(t2, 32, 64);
        t3 += __shfl_xor(t3, 16, 64); t3 += __shfl_xor(t3, 32, 64);
        float x20 = eluf(0.25f * t0 + b1v.x);
        float x21 = eluf(0.25f * t1 + b1v.y);
        float x22 = eluf(0.25f * t2 + b1v.z);
        float x23 = eluf(0.25f * t3 + b1v.w);
        float g = 0.f;
#pragma unroll
        for (int qq = 0; qq < 16; ++qq) {
            float xk0 = __shfl(x20, qq, 64);
            float xk1 = __shfl(x21, qq, 64);
            float xk2 = __shfl(x22, qq, 64);
            float xk3 = __shfl(x23, qq, 64);
            const float* w = W2s + (4 * qq) * 64 + lane;
            g += xk0 * w[0] + xk1 * w[64] + xk2 * w[128] + xk3 * w[192];
        }
        h2b[(size_t)n * 64 + lane] = f2bf(g);
        float ps = waveReduceSum(g * as2s[lane]);
        float pd = waveReduceSum(g * ad2s[lane]);
        if (lane == 0) {
            a_src2[n] = ps;
            a_dst2[n] = pd;
        }
    }
}

// ---------------- Layer 2 ----------------

// K8: fused layer-2 softmax-gather + self message + b2 + ELU -> out.
// Chunked (64 edges): coalesced preload of src + exp into LDS, broadcast reads.
__global__ void __launch_bounds__(256, 4)
k8_agg2(const int* __restrict__ off, const int* __restrict__ csr_src,
        const unsigned short* __restrict__ h2b,
        const float* __restrict__ a_src2, const float* __restrict__ a_dst2,
        const float* __restrict__ b2, float* __restrict__ out, int n_nodes) {
    __shared__ float b2s[64];
    __shared__ int   sS[4][64];
    __shared__ float eS[4][64];
    if (threadIdx.x < 64) b2s[threadIdx.x] = b2[threadIdx.x];
    __syncthreads();
    const int wave = threadIdx.x >> 6, lane = threadIdx.x & 63;
    for (int n = blockIdx.x * 4 + wave; n < n_nodes; n += gridDim.x * 4) {
        int beg = off[n], end = off[n + 1];
        float adn = a_dst2[n];
        float se = expf(leaky02(a_src2[n] + adn));
        float den = se;
        float acc = se * bf2f(h2b[(size_t)n * 64 + lane]);
        for (int base = beg; base < end; base += 64) {
            int m = end - base; if (m > 64) m = 64;
            if (lane < m) {
                int s = csr_src[base + lane];
                sS[wave][lane] = s;
                eS[wave][lane] = expf(leaky02(a_src2[s] + adn));
            }
            int i = 0;
            for (; i + 4 <= m; i += 4) {
                int s0 = sS[wave][i];
                int s1 = sS[wave][i + 1];
                int s2 = sS[wave][i + 2];
                int s3 = sS[wave][i + 3];
                float q0 = bf2f(h2b[(size_t)s0 * 64 + lane]);
                float q1 = bf2f(h2b[(size_t)s1 * 64 + lane]);
                float q2 = bf2f(h2b[(size_t)s2 * 64 + lane]);
                float q3 = bf2f(h2b[(size_t)s3 * 64 + lane]);
                float e0 = eS[wave][i];
                float e1 = eS[wave][i + 1];
                float e2 = eS[wave][i + 2];
                float e3 = eS[wave][i + 3];
                acc += e0 * q0 + e1 * q1 + e2 * q2 + e3 * q3;
                den += e0 + e1 + e2 + e3;
            }
            for (; i < m; ++i) {
                int s = sS[wave][i];
                float eh = eS[wave][i];
                acc += eh * bf2f(h2b[(size_t)s * 64 + lane]);
                den += eh;
            }
        }
        out[(size_t)n * 64 + lane] = eluf(acc / (den + 1e-16f) + b2s[lane]);
    }
}

extern "C" void kernel_launch(void* const* d_in, const int* in_sizes, int n_in,
                              void* d_out, int out_size, void* d_ws, size_t ws_size,
                              hipStream_t stream) {
    const float* x   = (const float*)d_in[0];
    const int*   ei  = (const int*)d_in[1];
    const float* W1  = (const float*)d_in[2];
    const float* as1 = (const float*)d_in[3];
    const float* ad1 = (const float*)d_in[4];
    const float* b1  = (const float*)d_in[5];
    const float* W2  = (const float*)d_in[6];
    const float* as2 = (const float*)d_in[7];
    const float* ad2 = (const float*)d_in[8];
    const float* b2  = (const float*)d_in[9];
    float* out = (float*)d_out;

    const int n = in_sizes[0] / 16;   // 50000
    const int e = in_sizes[1] / 2;    // 400000
    const int* src = ei;
    const int* dst = ei + e;
    const int nb = (n + 255) / 256;

    float* ws = (float*)d_ws;
    size_t o = 0;
    unsigned short* h1b = (unsigned short*)(ws + o); o += (size_t)n * 128;  // [N,256] bf16
    float*  a_src1  = ws + o; o += (size_t)n * 4;
    float*  a_dst1  = ws + o; o += (size_t)n * 4;
    unsigned short* h2b = (unsigned short*)(ws + o); o += (size_t)n * 32;   // [N,64] bf16
    float*  a_src2  = ws + o; o += (size_t)n;
    float*  a_dst2  = ws + o; o += (size_t)n;
    int*    csr_src = (int*)(ws + o); o += (size_t)e;
    int*    deg     = (int*)(ws + o); o += (size_t)n;
    int*    off     = (int*)(ws + o); o += (size_t)(n + 4);
    int*    cursor  = (int*)(ws + o); o += (size_t)n;
    int*    bsum    = (int*)(ws + o); o += 256;
    int*    bofs    = (int*)(ws + o); o += 256;

    hipMemsetAsync(deg, 0, (size_t)n * sizeof(int), stream);

    // CSR build (independent of features)
    k_deg<<<(e + 255) / 256, 256, 0, stream>>>(dst, deg, e);
    k_scan_bsums<<<nb, 256, 0, stream>>>(deg, bsum, n);
    k_scan_bofs<<<1, 256, 0, stream>>>(bsum, bofs, nb);
    k_scan_final<<<nb, 256, 0, stream>>>(deg, bofs, off, cursor, n, e);
    k3_scatter<<<(e + 255) / 256, 256, 0, stream>>>(src, dst, cursor, csr_src, e);

    // Layer 1
    k1_gemm1<<<(n + 3) / 4, 256, 0, stream>>>(x, W1, as1, ad1, h1b, a_src1, a_dst1, n);
    k4_agg1<<<(n + 3) / 4, 256, 0, stream>>>(off, csr_src, h1b, a_src1, a_dst1,
                                             b1, W2, as2, ad2, h2b, a_src2, a_dst2, n);

    // Layer 2
    k8_agg2<<<(n + 3) / 4, 256, 0, stream>>>(off, csr_src, h2b, a_src2, a_dst2, b2, out, n);
}

// Round 7
// 290.122 us; speedup vs baseline: 1.0489x; 1.0322x over previous
//
#include <hip/hip_runtime.h>
#include <math.h>

// ---------------------------------------------------------------------------
// 2-layer GAT encoder. CSR-by-dst gather aggregation (atomic-free).
// Round-7 change:
//  * Rounds 4-6 k4 carried ~90 MB of mystery HBM writes that appeared with
//    the in-k4 per-edge (a_src1 gather + expf) preload and survived both the
//    launch_bounds and LDS-exchange fixes. Revert the data flow to round-3
//    style: k3_scatter precomputes per-edge exp (csr_ex float4) once; k4's
//    chunk preload is now a pure coalesced copy (csr_src + csr_ex -> LDS),
//    keeping the x4-unrolled multi-gather inner loop from round 4.
// ---------------------------------------------------------------------------

__device__ __forceinline__ float leaky02(float x) { return x > 0.f ? x : 0.2f * x; }
__device__ __forceinline__ float eluf(float x) { return x > 0.f ? x : expm1f(x); }
__device__ __forceinline__ float waveReduceSum(float v) {
#pragma unroll
    for (int off = 32; off; off >>= 1) v += __shfl_xor(v, off, 64);
    return v;
}
__device__ __forceinline__ unsigned short f2bf(float f) {
    unsigned u = __float_as_uint(f);
    u += 0x7FFFu + ((u >> 16) & 1u);
    return (unsigned short)(u >> 16);
}
__device__ __forceinline__ float bf2f(unsigned short h) {
    return __uint_as_float((unsigned)h << 16);
}

// ---------------- CSR construction ----------------

__global__ void k_deg(const int* __restrict__ dst, int* __restrict__ deg, int e_cnt) {
    int e = blockIdx.x * blockDim.x + threadIdx.x;
    if (e < e_cnt) atomicAdd(&deg[dst[e]], 1);
}

__global__ void k_scan_bsums(const int* __restrict__ deg, int* __restrict__ bsum, int n) {
    __shared__ int part[4];
    int i = blockIdx.x * 256 + threadIdx.x;
    int v = (i < n) ? deg[i] : 0;
    int w = v;
#pragma unroll
    for (int off = 32; off; off >>= 1) w += __shfl_xor(w, off, 64);
    if ((threadIdx.x & 63) == 0) part[threadIdx.x >> 6] = w;
    __syncthreads();
    if (threadIdx.x == 0) bsum[blockIdx.x] = part[0] + part[1] + part[2] + part[3];
}

__global__ void k_scan_bofs(const int* __restrict__ bsum, int* __restrict__ bofs, int nb) {
    __shared__ int s[256];
    int t = threadIdx.x;
    int v = (t < nb) ? bsum[t] : 0;
    s[t] = v;
    __syncthreads();
#pragma unroll
    for (int d = 1; d < 256; d <<= 1) {
        int add = (t >= d) ? s[t - d] : 0;
        __syncthreads();
        s[t] += add;
        __syncthreads();
    }
    bofs[t] = s[t] - v;  // exclusive
}

__global__ void k_scan_final(const int* __restrict__ deg, const int* __restrict__ bofs,
                             int* __restrict__ off, int* __restrict__ cursor, int n, int e_cnt) {
    __shared__ int s[256];
    int t = threadIdx.x;
    int i = blockIdx.x * 256 + t;
    int v = (i < n) ? deg[i] : 0;
    s[t] = v;
    __syncthreads();
#pragma unroll
    for (int d = 1; d < 256; d <<= 1) {
        int add = (t >= d) ? s[t - d] : 0;
        __syncthreads();
        s[t] += add;
        __syncthreads();
    }
    int o = bofs[blockIdx.x] + s[t] - v;
    if (i < n) { off[i] = o; cursor[i] = o; }
    if (i == 0) off[n] = e_cnt;
}

// ---------------- Layer 1 ----------------

// K1: h1b (bf16, [N,256], channel c = 4*lane+j); a_src1/a_dst1 [N,4] fp32.
__global__ void k1_gemm1(const float* __restrict__ x, const float* __restrict__ W1,
                         const float* __restrict__ attS, const float* __restrict__ attD,
                         unsigned short* __restrict__ h1b, float* __restrict__ a_src1,
                         float* __restrict__ a_dst1, int n_nodes) {
    __shared__ float W1s[16 * 256];
    for (int i = threadIdx.x; i < 16 * 256; i += 256) W1s[i] = W1[i];
    __syncthreads();
    const int wave = threadIdx.x >> 6, lane = threadIdx.x & 63;
    const float4 aS = ((const float4*)attS)[lane];
    const float4 aD = ((const float4*)attD)[lane];
    for (int n = blockIdx.x * 4 + wave; n < n_nodes; n += gridDim.x * 4) {
        float xv = x[(size_t)n * 16 + (lane & 15)];
        float v0 = 0.f, v1 = 0.f, v2 = 0.f, v3 = 0.f;
#pragma unroll
        for (int k = 0; k < 16; ++k) {
            float xk = __shfl(xv, k, 64);
            const float* w = W1s + k * 256 + 4 * lane;
            v0 += xk * w[0]; v1 += xk * w[1]; v2 += xk * w[2]; v3 += xk * w[3];
        }
        ushort4 q;
        q.x = f2bf(v0); q.y = f2bf(v1); q.z = f2bf(v2); q.w = f2bf(v3);
        ((ushort4*)(h1b + (size_t)n * 256))[lane] = q;
        float ps = v0 * aS.x + v1 * aS.y + v2 * aS.z + v3 * aS.w;
        float pd = v0 * aD.x + v1 * aD.y + v2 * aD.z + v3 * aD.w;
#pragma unroll
        for (int off = 1; off < 16; off <<= 1) {
            ps += __shfl_xor(ps, off, 64);
            pd += __shfl_xor(pd, off, 64);
        }
        if ((lane & 15) == 0) {
            a_src1[n * 4 + (lane >> 4)] = ps;
            a_dst1[n * 4 + (lane >> 4)] = pd;
        }
    }
}

// K3: per-edge exp (4 heads) + scatter (src id, exp4) into CSR slot.
__global__ void k3_scatter(const int* __restrict__ src, const int* __restrict__ dst,
                           const float* __restrict__ a_src1, const float* __restrict__ a_dst1,
                           int* __restrict__ cursor, int* __restrict__ csr_src,
                           float4* __restrict__ csr_ex, int e_cnt) {
    int e = blockIdx.x * blockDim.x + threadIdx.x;
    if (e >= e_cnt) return;
    int s = src[e], d = dst[e];
    float4 as = *(const float4*)(a_src1 + (size_t)s * 4);
    float4 ad = *(const float4*)(a_dst1 + (size_t)d * 4);
    float4 ex;
    ex.x = expf(leaky02(as.x + ad.x));
    ex.y = expf(leaky02(as.y + ad.y));
    ex.z = expf(leaky02(as.z + ad.z));
    ex.w = expf(leaky02(as.w + ad.w));
    int pos = atomicAdd(&cursor[d], 1);
    csr_src[pos] = s;
    csr_ex[pos] = ex;
}

// K4: fused layer-1 softmax-gather + head-mean + b1 + ELU + GEMM2 + L2 scores.
// Wave per dst node; lane owns channels 4l..4l+3 (head = lane>>4).
// Chunk preload = pure coalesced copy (csr_src + csr_ex -> LDS); inner loop
// x4-unrolled with broadcast LDS reads.
__global__ void __launch_bounds__(256, 4)
k4_agg1(const int* __restrict__ off, const int* __restrict__ csr_src,
        const float4* __restrict__ csr_ex, const unsigned short* __restrict__ h1b,
        const float* __restrict__ a_src1, const float* __restrict__ a_dst1,
        const float* __restrict__ b1, const float* __restrict__ W2,
        const float* __restrict__ attS2, const float* __restrict__ attD2,
        unsigned short* __restrict__ h2b, float* __restrict__ a_src2,
        float* __restrict__ a_dst2, int n_nodes) {
    __shared__ float W2s[64 * 64];
    __shared__ float as2s[64], ad2s[64];
    __shared__ int   sS[4][16];   // per-wave chunk src ids
    __shared__ float eS[4][64];   // per-wave chunk exp4, [edge*4 + head]
    for (int i = threadIdx.x; i < 64 * 64; i += 256) W2s[i] = W2[i];
    if (threadIdx.x < 64) {
        as2s[threadIdx.x] = attS2[threadIdx.x];
        ad2s[threadIdx.x] = attD2[threadIdx.x];
    }
    __syncthreads();
    const int wave = threadIdx.x >> 6, lane = threadIdx.x & 63;
    const int head = lane >> 4;
    const float4 b1v = ((const float4*)b1)[lane & 15];
    for (int n = blockIdx.x * 4 + wave; n < n_nodes; n += gridDim.x * 4) {
        int beg = off[n], end = off[n + 1];
        float4 as = *(const float4*)(a_src1 + (size_t)n * 4);
        float4 ad = *(const float4*)(a_dst1 + (size_t)n * 4);
        float adh = head == 0 ? ad.x : head == 1 ? ad.y : head == 2 ? ad.z : ad.w;
        float ash = head == 0 ? as.x : head == 1 ? as.y : head == 2 ? as.z : as.w;
        float se = expf(leaky02(ash + adh));
        ushort4 qs = ((const ushort4*)(h1b + (size_t)n * 256))[lane];
        float den = se;
        float a0 = se * bf2f(qs.x), a1 = se * bf2f(qs.y);
        float a2 = se * bf2f(qs.z), a3 = se * bf2f(qs.w);
        for (int base = beg; base < end; base += 16) {
            int m = end - base; if (m > 16) m = 16;
            // pure coalesced preload: lanes 0..15 copy ids + exp4 into LDS
            if (lane < m) {
                sS[wave][lane] = csr_src[base + lane];
                ((float4*)eS[wave])[lane] = csr_ex[base + lane];
            }
            int i = 0;
            for (; i + 4 <= m; i += 4) {
                int s0 = sS[wave][i];
                int s1 = sS[wave][i + 1];
                int s2 = sS[wave][i + 2];
                int s3 = sS[wave][i + 3];
                ushort4 q0 = ((const ushort4*)(h1b + (size_t)s0 * 256))[lane];
                ushort4 q1 = ((const ushort4*)(h1b + (size_t)s1 * 256))[lane];
                ushort4 q2 = ((const ushort4*)(h1b + (size_t)s2 * 256))[lane];
                ushort4 q3 = ((const ushort4*)(h1b + (size_t)s3 * 256))[lane];
                float e0 = eS[wave][4 * i + head];
                float e1 = eS[wave][4 * (i + 1) + head];
                float e2 = eS[wave][4 * (i + 2) + head];
                float e3 = eS[wave][4 * (i + 3) + head];
                a0 += e0 * bf2f(q0.x) + e1 * bf2f(q1.x) + e2 * bf2f(q2.x) + e3 * bf2f(q3.x);
                a1 += e0 * bf2f(q0.y) + e1 * bf2f(q1.y) + e2 * bf2f(q2.y) + e3 * bf2f(q3.y);
                a2 += e0 * bf2f(q0.z) + e1 * bf2f(q1.z) + e2 * bf2f(q2.z) + e3 * bf2f(q3.z);
                a3 += e0 * bf2f(q0.w) + e1 * bf2f(q1.w) + e2 * bf2f(q2.w) + e3 * bf2f(q3.w);
                den += e0 + e1 + e2 + e3;
            }
            for (; i < m; ++i) {
                int s = sS[wave][i];
                float eh = eS[wave][4 * i + head];
                ushort4 q = ((const ushort4*)(h1b + (size_t)s * 256))[lane];
                a0 += eh * bf2f(q.x); a1 += eh * bf2f(q.y);
                a2 += eh * bf2f(q.z); a3 += eh * bf2f(q.w);
                den += eh;
            }
        }
        float inv = 1.f / (den + 1e-16f);
        float t0 = a0 * inv, t1 = a1 * inv, t2 = a2 * inv, t3 = a3 * inv;
        t0 += __shfl_xor(t0, 16, 64); t0 += __shfl_xor(t0, 32, 64);
        t1 += __shfl_xor(t1, 16, 64); t1 += __shfl_xor(t1, 32, 64);
        t2 += __shfl_xor(t2, 16, 64); t2 += __shfl_xor(t2, 32, 64);
        t3 += __shfl_xor(t3, 16, 64); t3 += __shfl_xor(t3, 32, 64);
        float x20 = eluf(0.25f * t0 + b1v.x);
        float x21 = eluf(0.25f * t1 + b1v.y);
        float x22 = eluf(0.25f * t2 + b1v.z);
        float x23 = eluf(0.25f * t3 + b1v.w);
        float g = 0.f;
#pragma unroll
        for (int qq = 0; qq < 16; ++qq) {
            float xk0 = __shfl(x20, qq, 64);
            float xk1 = __shfl(x21, qq, 64);
            float xk2 = __shfl(x22, qq, 64);
            float xk3 = __shfl(x23, qq, 64);
            const float* w = W2s + (4 * qq) * 64 + lane;
            g += xk0 * w[0] + xk1 * w[64] + xk2 * w[128] + xk3 * w[192];
        }
        h2b[(size_t)n * 64 + lane] = f2bf(g);
        float ps = waveReduceSum(g * as2s[lane]);
        float pd = waveReduceSum(g * ad2s[lane]);
        if (lane == 0) {
            a_src2[n] = ps;
            a_dst2[n] = pd;
        }
    }
}

// ---------------- Layer 2 ----------------

// K8: fused layer-2 softmax-gather + self message + b2 + ELU -> out.
// Chunked (64 edges): coalesced preload of src + exp into LDS, broadcast reads.
__global__ void __launch_bounds__(256, 4)
k8_agg2(const int* __restrict__ off, const int* __restrict__ csr_src,
        const unsigned short* __restrict__ h2b,
        const float* __restrict__ a_src2, const float* __restrict__ a_dst2,
        const float* __restrict__ b2, float* __restrict__ out, int n_nodes) {
    __shared__ float b2s[64];
    __shared__ int   sS[4][64];
    __shared__ float eS[4][64];
    if (threadIdx.x < 64) b2s[threadIdx.x] = b2[threadIdx.x];
    __syncthreads();
    const int wave = threadIdx.x >> 6, lane = threadIdx.x & 63;
    for (int n = blockIdx.x * 4 + wave; n < n_nodes; n += gridDim.x * 4) {
        int beg = off[n], end = off[n + 1];
        float adn = a_dst2[n];
        float se = expf(leaky02(a_src2[n] + adn));
        float den = se;
        float acc = se * bf2f(h2b[(size_t)n * 64 + lane]);
        for (int base = beg; base < end; base += 64) {
            int m = end - base; if (m > 64) m = 64;
            if (lane < m) {
                int s = csr_src[base + lane];
                sS[wave][lane] = s;
                eS[wave][lane] = expf(leaky02(a_src2[s] + adn));
            }
            int i = 0;
            for (; i + 4 <= m; i += 4) {
                int s0 = sS[wave][i];
                int s1 = sS[wave][i + 1];
                int s2 = sS[wave][i + 2];
                int s3 = sS[wave][i + 3];
                float q0 = bf2f(h2b[(size_t)s0 * 64 + lane]);
                float q1 = bf2f(h2b[(size_t)s1 * 64 + lane]);
                float q2 = bf2f(h2b[(size_t)s2 * 64 + lane]);
                float q3 = bf2f(h2b[(size_t)s3 * 64 + lane]);
                float e0 = eS[wave][i];
                float e1 = eS[wave][i + 1];
                float e2 = eS[wave][i + 2];
                float e3 = eS[wave][i + 3];
                acc += e0 * q0 + e1 * q1 + e2 * q2 + e3 * q3;
                den += e0 + e1 + e2 + e3;
            }
            for (; i < m; ++i) {
                int s = sS[wave][i];
                float eh = eS[wave][i];
                acc += eh * bf2f(h2b[(size_t)s * 64 + lane]);
                den += eh;
            }
        }
        out[(size_t)n * 64 + lane] = eluf(acc / (den + 1e-16f) + b2s[lane]);
    }
}

extern "C" void kernel_launch(void* const* d_in, const int* in_sizes, int n_in,
                              void* d_out, int out_size, void* d_ws, size_t ws_size,
                              hipStream_t stream) {
    const float* x   = (const float*)d_in[0];
    const int*   ei  = (const int*)d_in[1];
    const float* W1  = (const float*)d_in[2];
    const float* as1 = (const float*)d_in[3];
    const float* ad1 = (const float*)d_in[4];
    const float* b1  = (const float*)d_in[5];
    const float* W2  = (const float*)d_in[6];
    const float* as2 = (const float*)d_in[7];
    const float* ad2 = (const float*)d_in[8];
    const float* b2  = (const float*)d_in[9];
    float* out = (float*)d_out;

    const int n = in_sizes[0] / 16;   // 50000
    const int e = in_sizes[1] / 2;    // 400000
    const int* src = ei;
    const int* dst = ei + e;
    const int nb = (n + 255) / 256;

    float* ws = (float*)d_ws;
    size_t o = 0;
    unsigned short* h1b = (unsigned short*)(ws + o); o += (size_t)n * 128;  // [N,256] bf16
    float4* csr_ex  = (float4*)(ws + o); o += (size_t)e * 4;
    float*  a_src1  = ws + o; o += (size_t)n * 4;
    float*  a_dst1  = ws + o; o += (size_t)n * 4;
    unsigned short* h2b = (unsigned short*)(ws + o); o += (size_t)n * 32;   // [N,64] bf16
    float*  a_src2  = ws + o; o += (size_t)n;
    float*  a_dst2  = ws + o; o += (size_t)n;
    int*    csr_src = (int*)(ws + o); o += (size_t)e;
    int*    deg     = (int*)(ws + o); o += (size_t)n;
    int*    off     = (int*)(ws + o); o += (size_t)(n + 4);
    int*    cursor  = (int*)(ws + o); o += (size_t)n;
    int*    bsum    = (int*)(ws + o); o += 256;
    int*    bofs    = (int*)(ws + o); o += 256;

    hipMemsetAsync(deg, 0, (size_t)n * sizeof(int), stream);

    // CSR build (structure only)
    k_deg<<<(e + 255) / 256, 256, 0, stream>>>(dst, deg, e);
    k_scan_bsums<<<nb, 256, 0, stream>>>(deg, bsum, n);
    k_scan_bofs<<<1, 256, 0, stream>>>(bsum, bofs, nb);
    k_scan_final<<<nb, 256, 0, stream>>>(deg, bofs, off, cursor, n, e);

    // Layer 1
    k1_gemm1<<<(n + 3) / 4, 256, 0, stream>>>(x, W1, as1, ad1, h1b, a_src1, a_dst1, n);
    k3_scatter<<<(e + 255) / 256, 256, 0, stream>>>(src, dst, a_src1, a_dst1, cursor,
                                                    csr_src, csr_ex, e);
    k4_agg1<<<(n + 3) / 4, 256, 0, stream>>>(off, csr_src, csr_ex, h1b, a_src1, a_dst1,
                                             b1, W2, as2, ad2, h2b, a_src2, a_dst2, n);

    // Layer 2
    k8_agg2<<<(n + 3) / 4, 256, 0, stream>>>(off, csr_src, h2b, a_src2, a_dst2, b2, out, n);
}